// Round 6
// baseline (425.466 us; speedup 1.0000x reference)
//
#include <hip/hip_runtime.h>
#include <hip/hip_bf16.h>
#include <hip/hip_fp16.h>
#include <type_traits>

// ---------------------------------------------------------------------------
// GCN: out = relu(Agg(x@W1)+b1) -> relu(Agg(.@W2)+b2) -> .@Wc+bc
// Agg(h)[i] = dinv[i]^2*h[i] + sum_{e: dst=i} dinv[i]*dinv[src]*h[src]
// R1-R8: see history.
// R9 (FAILED, reverted): feature-sliced layout + XCD pinning -> 4x line amp.
// R10: split-K LDS (occupancy) -> NEUTRAL. gemm was concurrency-bound.
// R11: gemm_pf batch-issue pipeline -> gemm1 dropped out of top-5 (<65us);
//     total 414->395. agg pinned at 65.5us/FETCH 195MB (3rd confirmation).
// R12: (a) gemm_pf K-chunked B-staging (KC=128): LDS 67.6->34.8KB =
//     2->4 blocks/CU for gemm1, A batch-issue retained. (b) CSR split
//     arrays: eB u64 -> srcB u32 + dstB u8 (bucket id carries high bits):
//     -21MB traffic, smaller scatter txns. (c) agg: nontemporal srcS loads
//     + output stores (keep gather set in L2). agg structure frozen.
// ---------------------------------------------------------------------------

typedef _Float16 half8 __attribute__((ext_vector_type(8)));
typedef float floatx4 __attribute__((ext_vector_type(4)));
typedef unsigned int uint4v __attribute__((ext_vector_type(4)));

#define EPB 8192   // edges per block in histA/scatterA

// ------------------------- scan helpers (unchanged) ------------------------

__device__ inline int block_incl_scan_256(int t, int* tmp) {
    int tid = threadIdx.x;
    tmp[tid] = t;
    __syncthreads();
    #pragma unroll
    for (int off = 1; off < 256; off <<= 1) {
        int v = (tid >= off) ? tmp[tid - off] : 0;
        __syncthreads();
        tmp[tid] += v;
        __syncthreads();
    }
    return tmp[tid];
}

template <int ITEMS>
__global__ __launch_bounds__(256) void k_scan1(const int* __restrict__ v,
                                               int* __restrict__ bsum, int n) {
    __shared__ int tmp[256];
    int base = blockIdx.x * (256 * ITEMS) + threadIdx.x * ITEMS;
    int t = 0;
    #pragma unroll
    for (int l = 0; l < ITEMS; ++l) {
        int i = base + l;
        t += (i < n) ? v[i] : 0;
    }
    block_incl_scan_256(t, tmp);
    if (threadIdx.x == 0) bsum[blockIdx.x] = tmp[255];
}

__global__ __launch_bounds__(256) void k_scan2(int* __restrict__ bsum, int nb) {
    __shared__ int tmp[256];
    int tid = threadIdx.x;
    int v = (tid < nb) ? bsum[tid] : 0;
    block_incl_scan_256(v, tmp);
    if (tid < nb) bsum[tid] = tid ? tmp[tid - 1] : 0;
}

template <int ITEMS>
__global__ __launch_bounds__(256) void k_scan3(const int* __restrict__ vin,
                                               const int* __restrict__ bsum,
                                               int* __restrict__ rp, int n) {
    __shared__ int tmp[256];
    int base = blockIdx.x * (256 * ITEMS) + threadIdx.x * ITEMS;
    int v[ITEMS];
    int t = 0;
    #pragma unroll
    for (int l = 0; l < ITEMS; ++l) {
        int i = base + l;
        v[l] = (i < n) ? vin[i] : 0;
        t += v[l];
    }
    block_incl_scan_256(t, tmp);
    int run = bsum[blockIdx.x] + (threadIdx.x ? tmp[threadIdx.x - 1] : 0);
    #pragma unroll
    for (int l = 0; l < ITEMS; ++l) {
        int i = base + l;
        if (i < n) rp[i] = run;
        run += v[l];
    }
}

// ----------------------- bucket-sort CSR build -----------------------------

__global__ __launch_bounds__(256) void k_histA(const int* __restrict__ dst,
                                               int* __restrict__ histM,
                                               int E, int nblk) {
    __shared__ int h[512];
    int tid = threadIdx.x;
    for (int i = tid; i < 512; i += 256) h[i] = 0;
    __syncthreads();
    int base = blockIdx.x * EPB;
    #pragma unroll 4
    for (int l = 0; l < EPB / 256; ++l) {
        int i = base + l * 256 + tid;
        if (i < E) atomicAdd(&h[dst[i] >> 8], 1);
    }
    __syncthreads();
    for (int i = tid; i < 512; i += 256)
        histM[i * nblk + blockIdx.x] = h[i];
}

// scatter edges into bucket-grouped split arrays (src u32, dst-low u8);
// each (block,bucket) run is contiguous, no global atomics.
__global__ __launch_bounds__(256) void k_scatterA(const int* __restrict__ src,
                                                  const int* __restrict__ dst,
                                                  const int* __restrict__ histS,
                                                  unsigned int* __restrict__ srcB,
                                                  unsigned char* __restrict__ dstB,
                                                  int E, int nblk) {
    __shared__ int bse[512];
    __shared__ int cnt[512];
    int tid = threadIdx.x;
    for (int i = tid; i < 512; i += 256) {
        bse[i] = histS[i * nblk + blockIdx.x];
        cnt[i] = 0;
    }
    __syncthreads();
    int base = blockIdx.x * EPB;
    #pragma unroll 4
    for (int l = 0; l < EPB / 256; ++l) {
        int i = base + l * 256 + tid;
        if (i < E) {
            int d = dst[i];
            int s = src[i];
            int b = d >> 8;
            int r = atomicAdd(&cnt[b], 1);
            int pos = bse[b] + r;
            srcB[pos] = (unsigned)s;
            dstB[pos] = (unsigned char)(d & 255);
        }
    }
}

// one block per coarse bucket: LDS counting sort by dst&255 -> fully sorted;
// writes srcS coalesced; rowptr/deg/dinv via LDS bsearch on dst-low bytes.
#define BCAP 4608   // bucket capacity: mean 4096, sigma~64 -> 8 sigma head
__global__ __launch_bounds__(256) void k_sortB(const unsigned int* __restrict__ srcB,
                                               const unsigned char* __restrict__ dstB,
                                               const int* __restrict__ histS,
                                               int* __restrict__ srcS,
                                               int* __restrict__ rowptr,
                                               float* __restrict__ dinv,
                                               int n, int E, int nblk) {
    const int b   = blockIdx.x;
    const int tid = threadIdx.x;
    const int ni0 = b << 8;
    int s0 = histS[b * nblk];
    int s1 = (b < 511) ? histS[(b + 1) * nblk] : E;
    int cnt = s1 - s0;
    if (cnt > BCAP) cnt = BCAP;          // statistically unreachable
    if (cnt == 0 && ni0 > n) return;

    __shared__ int hist[256];
    __shared__ int tmp[256];
    __shared__ int baseA[256];
    __shared__ int cntA[256];
    __shared__ short dstL[BCAP];
    __shared__ unsigned srcL[BCAP];
    __shared__ int lbA[256];

    hist[tid] = 0;
    cntA[tid] = 0;
    __syncthreads();
    for (int i = s0 + tid; i < s0 + cnt; i += 256)
        atomicAdd(&hist[dstB[i]], 1);
    __syncthreads();
    int own  = hist[tid];
    int incl = block_incl_scan_256(own, tmp);
    baseA[tid] = incl - own;
    __syncthreads();
    for (int i = s0 + tid; i < s0 + cnt; i += 256) {
        int dig = dstB[i];
        unsigned s = srcB[i];
        int r = atomicAdd(&cntA[dig], 1);
        int pos = baseA[dig] + r;
        dstL[pos] = (short)dig;
        srcL[pos] = s;
    }
    __syncthreads();
    // coalesced src emit
    for (int j = tid; j < cnt; j += 256)
        srcS[s0 + j] = (int)srcL[j];
    // rowptr / dinv for nodes [ni0, ni0+256) (and rowptr[n] if it falls here)
    if (ni0 <= n) {
        int i = ni0 + tid;
        int lo = 0, hi = cnt;
        while (lo < hi) {
            int mid = (lo + hi) >> 1;
            if ((int)dstL[mid] < tid) lo = mid + 1; else hi = mid;
        }
        lbA[tid] = lo;
        __syncthreads();
        if (i <= n) {
            rowptr[i] = s0 + lo;
            if (i < n) {
                int ub = (tid < 255) ? lbA[tid + 1] : cnt;
                dinv[i] = rsqrtf((float)(ub - lo + 1));
            }
        }
    }
}

// All three weight casts fused: W[K][N] fp32 -> Wt[NP][K] fp16 (zero-pad).
__global__ __launch_bounds__(256) void k_wcast_all(const float* __restrict__ W1,
                                                   _Float16* __restrict__ W1t,
                                                   const float* __restrict__ W2,
                                                   _Float16* __restrict__ W2t,
                                                   const float* __restrict__ Wc,
                                                   _Float16* __restrict__ Wct) {
    int i = blockIdx.x * 256 + threadIdx.x;
    if (i < 32768) {
        int c = i >> 8, k = i & 255;
        W1t[i] = (_Float16)W1[(size_t)k * 128 + c];
    } else if (i < 32768 + 16384) {
        int j = i - 32768;
        int c = j >> 7, k = j & 127;
        W2t[j] = (_Float16)W2[(size_t)k * 128 + c];
    } else if (i < 32768 + 16384 + 6144) {
        int j = i - 32768 - 16384;
        int c = j >> 7, k = j & 127;
        Wct[j] = (c < 40) ? (_Float16)Wc[(size_t)k * 40 + c] : (_Float16)0.f;
    }
}

// ----------------------- MFMA GEMM (batch-issue pipeline) ------------------
// C[M,N] = A[M,K] @ W[K,N] via v_mfma_f32_16x16x32_f16.
// Per lane: ALL A loads for its row segment issued first (single base +
// imm offsets), then Wt staged to LDS in KC=128 chunks (34.8KB -> 4
// blocks/CU), then cvt+MFMA. Latency hidden by A-batching AND block
// overlap. One wave = 16 rows x BN cols; block = 64 rows.

template <int K, int BN, typename AT, typename OT>
__global__ __launch_bounds__(256) void gemm_pf(const AT* __restrict__ A,
                                               const _Float16* __restrict__ Wt,
                                               const float* __restrict__ bias,
                                               OT* __restrict__ C,
                                               int M, int N) {
    constexpr int KC = (K > 128) ? 128 : K;   // LDS K-chunk
    constexpr int KP = KC + 8;
    constexpr int NT = BN / 16;
    constexpr int KS = K / 32;
    __shared__ __align__(16) _Float16 Bs[BN * KP];

    const int tid  = threadIdx.x;
    const int lane = tid & 63;
    const int wv   = tid >> 6;
    const int qd   = lane >> 4;
    const int ln15 = lane & 15;
    const int bm   = blockIdx.x * 64;

    int row  = bm + wv * 16 + ln15;
    int rowc = (row < M) ? row : (M - 1);   // clamp: loads safe, stores guarded

    // (1) issue ALL A loads back-to-back (independent, one base each)
    float4 af[std::is_same<AT, float>::value ? KS : 1][2];
    half8  ah[std::is_same<AT, float>::value ? 1 : KS];
    if constexpr (std::is_same<AT, float>::value) {
        const float* p = A + (size_t)rowc * K + qd * 8;
        #pragma unroll
        for (int ks = 0; ks < KS; ++ks) {
            af[ks][0] = *(const float4*)(p + ks * 32);
            af[ks][1] = *(const float4*)(p + ks * 32 + 4);
        }
    } else {
        const _Float16* p = (const _Float16*)A + (size_t)rowc * K + qd * 8;
        #pragma unroll
        for (int ks = 0; ks < KS; ++ks)
            ah[ks] = *(const half8*)(p + ks * 32);
    }

    floatx4 acc[NT];
    #pragma unroll
    for (int c = 0; c < NT; ++c) acc[c] = (floatx4){0.f, 0.f, 0.f, 0.f};

    // (2) per K-chunk: stage Wt slice, barrier, MFMA
    #pragma unroll
    for (int kh = 0; kh < K; kh += KC) {
        if (kh) __syncthreads();   // protect Bs before overwrite
        constexpr int TOT = BN * KC / 8;
        #pragma unroll
        for (int i = 0; i < TOT / 256; ++i) {
            int idx = (i * 256 + tid) * 8;
            int col = idx / KC;
            int kk  = idx % KC;
            *(uint4*)&Bs[col * KP + kk] =
                *(const uint4*)(Wt + (size_t)col * K + kh + kk);
        }
        __syncthreads();

        #pragma unroll
        for (int ks2 = 0; ks2 < KC / 32; ++ks2) {
            const int ks = kh / 32 + ks2;
            half8 a;
            if constexpr (std::is_same<AT, float>::value) {
                float4 v0 = af[ks][0];
                float4 v1 = af[ks][1];
                a[0] = (_Float16)v0.x; a[1] = (_Float16)v0.y;
                a[2] = (_Float16)v0.z; a[3] = (_Float16)v0.w;
                a[4] = (_Float16)v1.x; a[5] = (_Float16)v1.y;
                a[6] = (_Float16)v1.z; a[7] = (_Float16)v1.w;
            } else {
                a = ah[ks];
            }
            #pragma unroll
            for (int c = 0; c < NT; ++c) {
                half8 b = *(const half8*)&Bs[(c * 16 + ln15) * KP + ks2 * 32 + qd * 8];
                acc[c] = __builtin_amdgcn_mfma_f32_16x16x32_f16(a, b, acc[c], 0, 0, 0);
            }
        }
    }

    // (3) epilogue
    int baseRow = bm + wv * 16 + qd * 4;
    #pragma unroll
    for (int c = 0; c < NT; ++c) {
        int col = c * 16 + ln15;
        if constexpr (std::is_same<OT, _Float16>::value) {
            #pragma unroll
            for (int r = 0; r < 4; ++r) {
                int rr = baseRow + r;
                if (rr < M) C[(size_t)rr * N + col] = (_Float16)acc[c][r];
            }
        } else {
            float bv = (col < N && bias) ? bias[col] : 0.f;
            #pragma unroll
            for (int r = 0; r < 4; ++r) {
                int rr = baseRow + r;
                if (rr < M && col < N)
                    ((float*)C)[(size_t)rr * N + col] = acc[c][r] + bv;
            }
        }
    }
}

// ---------------------------- aggregation ----------------------------------
// R7 structure (pattern ceiling ~65us; frozen): one wave per node; 4 groups
// x 16 lanes; group owns one edge per step, lane loads dwordx4 (8 fp16
// cols); ds_bpermute broadcast; cross-group shfl_xor(16,32) reduce.
// R12: nontemporal srcS loads + output stores (don't evict gather set).

static __device__ __forceinline__ float2 h2f2u(unsigned int raw) {
    __half2 h = *(__half2*)&raw;
    return __half22float2(h);
}

__global__ __launch_bounds__(256) void gcn_agg(const unsigned int* __restrict__ h,
                                               const int* __restrict__ rowptr,
                                               const int* __restrict__ srcS,
                                               const float* __restrict__ dinv,
                                               const float* __restrict__ bias,
                                               unsigned int* __restrict__ out,
                                               int n, int do_relu) {
    int node = blockIdx.x * 4 + (threadIdx.x >> 6);
    if (node >= n) return;
    const int lane = threadIdx.x & 63;
    const int g    = lane >> 4;      // edge group 0..3
    const int t    = lane & 15;      // col chunk: cols [t*8, t*8+8)

    const _Float16* hb = (const _Float16*)h;

    float di = dinv[node];
    int e0 = rowptr[node];
    int e1 = rowptr[node + 1];

    half8 sv = *(const half8*)(hb + (size_t)(unsigned)node * 128 + t * 8);
    const float4* b4 = (const float4*)bias;
    float4 blo = b4[t * 2 + 0];
    float4 bhi = b4[t * 2 + 1];

    float2 acc[4];
    #pragma unroll
    for (int i = 0; i < 4; ++i) acc[i] = make_float2(0.f, 0.f);

    for (int ce = e0; ce < e1; ce += 64) {
        int cnt = e1 - ce;
        cnt = (cnt < 64) ? cnt : 64;
        int colv = 0, wval = 0;
        if (lane < cnt) {
            int c = __builtin_nontemporal_load(srcS + ce + lane);
            colv = c;
            wval = __float_as_int(di * dinv[c]);
        }
        #pragma unroll 2
        for (int d = 0; d < cnt; d += 4) {
            int idx = (d + g) << 2;
            int c   = __builtin_amdgcn_ds_bpermute(idx, colv);
            float w = __int_as_float(__builtin_amdgcn_ds_bpermute(idx, wval));
            const unsigned* hp = (const unsigned*)(hb + (size_t)(unsigned)c * 128 + t * 8);
            uint4 hv = *(const uint4*)hp;
            float2 u0 = h2f2u(hv.x);
            float2 u1 = h2f2u(hv.y);
            float2 u2 = h2f2u(hv.z);
            float2 u3 = h2f2u(hv.w);
            acc[0].x += u0.x * w; acc[0].y += u0.y * w;
            acc[1].x += u1.x * w; acc[1].y += u1.y * w;
            acc[2].x += u2.x * w; acc[2].y += u2.y * w;
            acc[3].x += u3.x * w; acc[3].y += u3.y * w;
        }
    }

    #pragma unroll
    for (int i = 0; i < 4; ++i) {
        acc[i].x += __shfl_xor(acc[i].x, 16);
        acc[i].y += __shfl_xor(acc[i].y, 16);
        acc[i].x += __shfl_xor(acc[i].x, 32);
        acc[i].y += __shfl_xor(acc[i].y, 32);
    }

    float s = di * di;
    float bb[8] = {blo.x, blo.y, blo.z, blo.w, bhi.x, bhi.y, bhi.z, bhi.w};
    half8 o;
    #pragma unroll
    for (int i = 0; i < 8; ++i) {
        float v = ((i & 1) ? acc[i >> 1].y : acc[i >> 1].x) + (float)sv[i] * s + bb[i];
        if (do_relu) v = fmaxf(v, 0.f);
        o[i] = (_Float16)v;
    }
    if (g == 0) {
        uint4v* dstp = (uint4v*)((_Float16*)out + (size_t)(unsigned)node * 128 + t * 8);
        __builtin_nontemporal_store(*(uint4v*)&o, dstp);
    }
}

// ------------------------------- launch ------------------------------------

extern "C" void kernel_launch(void* const* d_in, const int* in_sizes, int n_in,
                              void* d_out, int out_size, void* d_ws, size_t ws_size,
                              hipStream_t stream) {
    const float* x  = (const float*)d_in[0];
    const int* eidx = (const int*)d_in[1];
    const float* W1 = (const float*)d_in[2];
    const float* b1 = (const float*)d_in[3];
    const float* W2 = (const float*)d_in[4];
    const float* b2 = (const float*)d_in[5];
    const float* Wc = (const float*)d_in[6];
    const float* bc = (const float*)d_in[7];
    float* out = (float*)d_out;

    const int NF = 256, NH = 128, NC = 40;
    const int n = in_sizes[0] / NF;    // 100000
    const int E = in_sizes[1] / 2;     // 1600000
    const int* src = eidx;
    const int* dst = eidx + E;

    const int nblk = (E + EPB - 1) / EPB;          // 196
    const int hm   = 512 * nblk;                   // 100352
    const int nbA  = (hm + 4095) / 4096;           // 25

    char* wsb = (char*)d_ws;
    size_t off = 0;
    auto alloc = [&](size_t bytes) {
        char* p = wsb + off;
        off = (off + bytes + 511) & ~(size_t)511;
        return p;
    };
    _Float16* hbuf = (_Float16*)alloc((size_t)n * NH * 2);  // 25.6 MB
    _Float16* abuf = (_Float16*)alloc((size_t)n * NH * 2);  // 25.6 MB
    _Float16* W1t  = (_Float16*)alloc((size_t)128 * 256 * 2);
    _Float16* W2t  = (_Float16*)alloc((size_t)128 * 128 * 2);
    _Float16* Wct  = (_Float16*)alloc((size_t)48 * 128 * 2);
    unsigned int* srcB  = (unsigned int*)alloc((size_t)E * 4);   // 6.4 MB
    unsigned char* dstB = (unsigned char*)alloc((size_t)E);      // 1.6 MB
    int* srcS      = (int*)alloc((size_t)E * 4);                 // 6.4 MB
    int* histM     = (int*)alloc((size_t)hm * 4);
    int* histS     = (int*)alloc((size_t)hm * 4);
    int* rowptr    = (int*)alloc((size_t)(n + 1) * 4);
    float* dinv    = (float*)alloc((size_t)n * 4);
    int* bsumA     = (int*)alloc(1024);

    // ---- CSR build: 2-level bucket sort, no global atomics ----
    k_histA<<<nblk, 256, 0, stream>>>(dst, histM, E, nblk);
    k_scan1<16><<<nbA, 256, 0, stream>>>(histM, bsumA, hm);
    k_scan2<<<1, 256, 0, stream>>>(bsumA, nbA);
    k_scan3<16><<<nbA, 256, 0, stream>>>(histM, bsumA, histS, hm);
    k_scatterA<<<nblk, 256, 0, stream>>>(src, dst, histS, srcB, dstB, E, nblk);
    k_sortB<<<512, 256, 0, stream>>>(srcB, dstB, histS, srcS, rowptr, dinv, n, E, nblk);

    // ---- weights (fused) ----
    k_wcast_all<<<(32768 + 16384 + 6144 + 255) / 256, 256, 0, stream>>>(
        W1, W1t, W2, W2t, Wc, Wct);

    // ---- layers ----
    const int gB = (n + 63) / 64;   // 1563 blocks, 64 rows each
    gemm_pf<256, 128, float, _Float16><<<gB, 256, 0, stream>>>(x, W1t, nullptr, hbuf, n, NH);
    gcn_agg<<<(n + 3) / 4, 256, 0, stream>>>((const unsigned int*)hbuf, rowptr, srcS, dinv, b1,
                                             (unsigned int*)abuf, n, 1);
    gemm_pf<128, 128, _Float16, _Float16><<<gB, 256, 0, stream>>>(abuf, W2t, nullptr, hbuf, n, NH);
    gcn_agg<<<(n + 3) / 4, 256, 0, stream>>>((const unsigned int*)hbuf, rowptr, srcS, dinv, b2,
                                             (unsigned int*)abuf, n, 1);
    gemm_pf<128, 48, _Float16, float><<<gB, 256, 0, stream>>>(abuf, Wct, bc, out, n, NC);
}

// Round 9
// 399.066 us; speedup vs baseline: 1.0662x; 1.0662x over previous
//
#include <hip/hip_runtime.h>
#include <hip/hip_bf16.h>
#include <hip/hip_fp16.h>
#include <type_traits>

// ---------------------------------------------------------------------------
// GCN: out = relu(Agg(x@W1)+b1) -> relu(Agg(.@W2)+b2) -> .@Wc+bc
// Agg(h)[i] = dinv[i]^2*h[i] + sum_{e: dst=i} dinv[i]*dinv[src]*h[src]
// R1-R8: see history.
// R9 (FAILED): feature-sliced layout + XCD pinning -> 4x line amp. Reverted.
// R10: split-K LDS (occupancy) -> NEUTRAL; gemm was concurrency-bound.
// R11: gemm_pf batch-issue pipeline -> total 395us (best). agg 65.5us,
//     FETCH 195MB (4th confirmation of pattern ceiling). agg FROZEN.
// R12 (FAILED, reverted): nontemporal agg / K-chunked gemm / split CSR.
// R13 (CRASHED): 128-node buckets with BCAP=2048 == MEAN load -> ~half the
//     buckets clamped -> srcS tails uninitialized -> OOB gather abort.
// R14: BCAP 2560 (+11.3 sigma, overflow ~1e-28). Bench died with a
//     container-level failure (no pytest output) -> infra flake suspected;
//     full audit found no bug (rowptr[n] via bucket 781 OK, scan3f OK).
// R15: R14 resubmitted + defensive index clamp in gcn_agg fetch stage
//     (unsigned min vs n-1, 1 VALU/64-edges/lane, off the gather critical
//     path): any future CSR bug degrades to wrong-answer, not OOB crash.
// ---------------------------------------------------------------------------

typedef _Float16 half8 __attribute__((ext_vector_type(8)));
typedef float floatx4 __attribute__((ext_vector_type(4)));

#define EPB 8192    // edges per block in histA/scatterA
#define NBKT 1024   // coarse buckets (dst>>7), 128 nodes each (782 occupied)
#define BCAP 2560   // bucket capacity: mean 2048, sigma~45 -> +11 sigma

// ------------------------- scan helpers ------------------------------------

__device__ inline int block_incl_scan_256(int t, int* tmp) {
    int tid = threadIdx.x;
    tmp[tid] = t;
    __syncthreads();
    #pragma unroll
    for (int off = 1; off < 256; off <<= 1) {
        int v = (tid >= off) ? tmp[tid - off] : 0;
        __syncthreads();
        tmp[tid] += v;
        __syncthreads();
    }
    return tmp[tid];
}

template <int ITEMS>
__global__ __launch_bounds__(256) void k_scan1(const int* __restrict__ v,
                                               int* __restrict__ bsum, int n) {
    __shared__ int tmp[256];
    int base = blockIdx.x * (256 * ITEMS) + threadIdx.x * ITEMS;
    int t = 0;
    #pragma unroll
    for (int l = 0; l < ITEMS; ++l) {
        int i = base + l;
        t += (i < n) ? v[i] : 0;
    }
    block_incl_scan_256(t, tmp);
    if (threadIdx.x == 0) bsum[blockIdx.x] = tmp[255];
}

// scan3 with inlined block-sum prefix (replaces old k_scan2 + k_scan3):
// bsum[] holds per-block TOTALS from scan1; each block first computes the
// sum of totals of preceding blocks via one in-LDS scan.
template <int ITEMS>
__global__ __launch_bounds__(256) void k_scan3f(const int* __restrict__ vin,
                                                const int* __restrict__ bsum,
                                                int* __restrict__ rp, int n, int nb) {
    __shared__ int tmp[256];
    int tid = threadIdx.x;
    int bs = (tid < nb && tid < (int)blockIdx.x) ? bsum[tid] : 0;
    block_incl_scan_256(bs, tmp);
    int base0 = tmp[255];
    __syncthreads();   // protect tmp before reuse

    int base = blockIdx.x * (256 * ITEMS) + tid * ITEMS;
    int v[ITEMS];
    int t = 0;
    #pragma unroll
    for (int l = 0; l < ITEMS; ++l) {
        int i = base + l;
        v[l] = (i < n) ? vin[i] : 0;
        t += v[l];
    }
    int incl = block_incl_scan_256(t, tmp);
    int run = base0 + incl - t;
    #pragma unroll
    for (int l = 0; l < ITEMS; ++l) {
        int i = base + l;
        if (i < n) rp[i] = run;
        run += v[l];
    }
}

// ----------------------- bucket-sort CSR build -----------------------------

__global__ __launch_bounds__(256) void k_histA(const int* __restrict__ dst,
                                               int* __restrict__ histM,
                                               int E, int nblk) {
    __shared__ int h[NBKT];
    int tid = threadIdx.x;
    for (int i = tid; i < NBKT; i += 256) h[i] = 0;
    __syncthreads();
    int base = blockIdx.x * EPB;
    #pragma unroll 4
    for (int l = 0; l < EPB / 256; ++l) {
        int i = base + l * 256 + tid;
        if (i < E) atomicAdd(&h[dst[i] >> 7], 1);
    }
    __syncthreads();
    for (int i = tid; i < NBKT; i += 256)
        histM[i * nblk + blockIdx.x] = h[i];
}

// scatter edges into bucket-grouped u64 array; each (block,bucket) run is
// contiguous (~8 edges = one 64B line), no global atomics.
__global__ __launch_bounds__(256) void k_scatterA(const int* __restrict__ src,
                                                  const int* __restrict__ dst,
                                                  const int* __restrict__ histS,
                                                  unsigned long long* __restrict__ eB,
                                                  int E, int nblk) {
    __shared__ int bse[NBKT];
    __shared__ int cnt[NBKT];
    int tid = threadIdx.x;
    for (int i = tid; i < NBKT; i += 256) {
        bse[i] = histS[i * nblk + blockIdx.x];
        cnt[i] = 0;
    }
    __syncthreads();
    int base = blockIdx.x * EPB;
    #pragma unroll 4
    for (int l = 0; l < EPB / 256; ++l) {
        int i = base + l * 256 + tid;
        if (i < E) {
            int d = dst[i];
            int s = src[i];
            int b = d >> 7;
            int r = atomicAdd(&cnt[b], 1);
            eB[bse[b] + r] = ((unsigned long long)(unsigned)d << 32) | (unsigned)s;
        }
    }
}

// one block per bucket (128 nodes): LDS counting sort by dst&127; emits
// srcS coalesced; rowptr/deg/dinv via LDS bsearch on sorted digits.
__global__ __launch_bounds__(256) void k_sortB(const unsigned long long* __restrict__ eB,
                                               const int* __restrict__ histS,
                                               int* __restrict__ srcS,
                                               int* __restrict__ rowptr,
                                               float* __restrict__ dinv,
                                               int n, int E, int nblk) {
    const int b   = blockIdx.x;
    const int tid = threadIdx.x;
    const int ni0 = b << 7;
    int s0 = histS[b * nblk];
    int s1 = (b < NBKT - 1) ? histS[(b + 1) * nblk] : E;
    int cnt = s1 - s0;
    if (cnt > BCAP) cnt = BCAP;          // statistically unreachable (+11 sigma)
    if (cnt == 0 && ni0 > n) return;

    __shared__ int hist[256];
    __shared__ int tmp[256];
    __shared__ int baseA[256];
    __shared__ int cntA[256];
    __shared__ short dstL[BCAP];
    __shared__ unsigned srcL[BCAP];
    __shared__ int lbA[128];

    hist[tid] = 0;
    cntA[tid] = 0;
    __syncthreads();
    for (int i = s0 + tid; i < s0 + cnt; i += 256)
        atomicAdd(&hist[(int)(eB[i] >> 32) & 127], 1);
    __syncthreads();
    int own  = hist[tid];
    int incl = block_incl_scan_256(own, tmp);
    baseA[tid] = incl - own;
    __syncthreads();
    for (int i = s0 + tid; i < s0 + cnt; i += 256) {
        unsigned long long v = eB[i];
        int dig = (int)(v >> 32) & 127;
        int r = atomicAdd(&cntA[dig], 1);
        int pos = baseA[dig] + r;
        dstL[pos] = (short)dig;
        srcL[pos] = (unsigned)v;
    }
    __syncthreads();
    // coalesced src emit
    for (int j = tid; j < cnt; j += 256)
        srcS[s0 + j] = (int)srcL[j];
    // rowptr / dinv for nodes [ni0, ni0+128) (and rowptr[n] if it falls here)
    if (ni0 <= n) {
        if (tid < 128) {
            int lo = 0, hi = cnt;
            while (lo < hi) {
                int mid = (lo + hi) >> 1;
                if ((int)dstL[mid] < tid) lo = mid + 1; else hi = mid;
            }
            lbA[tid] = lo;
        }
        __syncthreads();
        if (tid < 128) {
            int i = ni0 + tid;
            if (i <= n) {
                int lo = lbA[tid];
                rowptr[i] = s0 + lo;
                if (i < n) {
                    int ub = (tid < 127) ? lbA[tid + 1] : cnt;
                    dinv[i] = rsqrtf((float)(ub - lo + 1));
                }
            }
        }
    }
}

// All three weight casts fused: W[K][N] fp32 -> Wt[NP][K] fp16 (zero-pad).
__global__ __launch_bounds__(256) void k_wcast_all(const float* __restrict__ W1,
                                                   _Float16* __restrict__ W1t,
                                                   const float* __restrict__ W2,
                                                   _Float16* __restrict__ W2t,
                                                   const float* __restrict__ Wc,
                                                   _Float16* __restrict__ Wct) {
    int i = blockIdx.x * 256 + threadIdx.x;
    if (i < 32768) {
        int c = i >> 8, k = i & 255;
        W1t[i] = (_Float16)W1[(size_t)k * 128 + c];
    } else if (i < 32768 + 16384) {
        int j = i - 32768;
        int c = j >> 7, k = j & 127;
        W2t[j] = (_Float16)W2[(size_t)k * 128 + c];
    } else if (i < 32768 + 16384 + 6144) {
        int j = i - 32768 - 16384;
        int c = j >> 7, k = j & 127;
        Wct[j] = (c < 40) ? (_Float16)Wc[(size_t)k * 40 + c] : (_Float16)0.f;
    }
}

// ----------------------- MFMA GEMM (batch-issue pipeline, R11) -------------
// C[M,N] = A[M,K] @ W[K,N] via v_mfma_f32_16x16x32_f16.
// Per lane: ALL A loads for its row segment issued first (single base +
// imm offsets), then Wt staged to LDS (single shot), ONE barrier, then
// pure cvt+MFMA loop. 16KB/wave VMEM in flight. Wave = 16 rows x BN cols.

template <int K, int BN, typename AT, typename OT>
__global__ __launch_bounds__(256) void gemm_pf(const AT* __restrict__ A,
                                               const _Float16* __restrict__ Wt,
                                               const float* __restrict__ bias,
                                               OT* __restrict__ C,
                                               int M, int N) {
    constexpr int KP = K + 8;
    constexpr int NT = BN / 16;
    constexpr int KS = K / 32;
    __shared__ __align__(16) _Float16 Bs[BN * KP];

    const int tid  = threadIdx.x;
    const int lane = tid & 63;
    const int wv   = tid >> 6;
    const int qd   = lane >> 4;
    const int ln15 = lane & 15;
    const int bm   = blockIdx.x * 64;

    int row  = bm + wv * 16 + ln15;
    int rowc = (row < M) ? row : (M - 1);   // clamp: loads safe, stores guarded

    // (1) issue ALL A loads back-to-back (independent, one base each)
    float4 af[std::is_same<AT, float>::value ? KS : 1][2];
    half8  ah[std::is_same<AT, float>::value ? 1 : KS];
    if constexpr (std::is_same<AT, float>::value) {
        const float* p = A + (size_t)rowc * K + qd * 8;
        #pragma unroll
        for (int ks = 0; ks < KS; ++ks) {
            af[ks][0] = *(const float4*)(p + ks * 32);
            af[ks][1] = *(const float4*)(p + ks * 32 + 4);
        }
    } else {
        const _Float16* p = (const _Float16*)A + (size_t)rowc * K + qd * 8;
        #pragma unroll
        for (int ks = 0; ks < KS; ++ks)
            ah[ks] = *(const half8*)(p + ks * 32);
    }

    // (2) stage all of Wt into LDS
    constexpr int TOT = BN * K / 8;
    #pragma unroll
    for (int i = 0; i < TOT / 256; ++i) {
        int idx = (i * 256 + tid) * 8;
        int col = idx / K;
        int kk  = idx % K;
        *(uint4*)&Bs[col * KP + kk] = *(const uint4*)(Wt + idx);
    }
    __syncthreads();

    // (3) pure MFMA loop
    floatx4 acc[NT];
    #pragma unroll
    for (int c = 0; c < NT; ++c) acc[c] = (floatx4){0.f, 0.f, 0.f, 0.f};

    #pragma unroll
    for (int ks = 0; ks < KS; ++ks) {
        half8 a;
        if constexpr (std::is_same<AT, float>::value) {
            float4 v0 = af[ks][0];
            float4 v1 = af[ks][1];
            a[0] = (_Float16)v0.x; a[1] = (_Float16)v0.y;
            a[2] = (_Float16)v0.z; a[3] = (_Float16)v0.w;
            a[4] = (_Float16)v1.x; a[5] = (_Float16)v1.y;
            a[6] = (_Float16)v1.z; a[7] = (_Float16)v1.w;
        } else {
            a = ah[ks];
        }
        #pragma unroll
        for (int c = 0; c < NT; ++c) {
            half8 b = *(const half8*)&Bs[(c * 16 + ln15) * KP + ks * 32 + qd * 8];
            acc[c] = __builtin_amdgcn_mfma_f32_16x16x32_f16(a, b, acc[c], 0, 0, 0);
        }
    }

    // (4) epilogue
    int baseRow = bm + wv * 16 + qd * 4;
    #pragma unroll
    for (int c = 0; c < NT; ++c) {
        int col = c * 16 + ln15;
        if constexpr (std::is_same<OT, _Float16>::value) {
            #pragma unroll
            for (int r = 0; r < 4; ++r) {
                int rr = baseRow + r;
                if (rr < M) C[(size_t)rr * N + col] = (_Float16)acc[c][r];
            }
        } else {
            float bv = (col < N && bias) ? bias[col] : 0.f;
            #pragma unroll
            for (int r = 0; r < 4; ++r) {
                int rr = baseRow + r;
                if (rr < M && col < N)
                    ((float*)C)[(size_t)rr * N + col] = acc[c][r] + bv;
            }
        }
    }
}

// ---------------------------- aggregation (R11, FROZEN) --------------------
// One wave per node; 4 groups x 16 lanes; group owns one edge per step,
// lane loads dwordx4 (8 fp16 cols); ds_bpermute broadcast; cross-group
// shfl_xor(16,32) reduce. ~1.5x of the TA lane-request floor (~42us);
// FETCH pinned at 195MB across 4 structural variants.
// R15: fetched index clamped to [0,n) (defense vs CSR bugs; off critical
// path -- one unsigned min per 64 edges per lane).

static __device__ __forceinline__ float2 h2f2u(unsigned int raw) {
    __half2 h = *(__half2*)&raw;
    return __half22float2(h);
}

__global__ __launch_bounds__(256) void gcn_agg(const unsigned int* __restrict__ h,
                                               const int* __restrict__ rowptr,
                                               const int* __restrict__ srcS,
                                               const float* __restrict__ dinv,
                                               const float* __restrict__ bias,
                                               unsigned int* __restrict__ out,
                                               int n, int do_relu) {
    int node = blockIdx.x * 4 + (threadIdx.x >> 6);
    if (node >= n) return;
    const int lane = threadIdx.x & 63;
    const int g    = lane >> 4;      // edge group 0..3
    const int t    = lane & 15;      // col chunk: cols [t*8, t*8+8)

    const _Float16* hb = (const _Float16*)h;

    float di = dinv[node];
    int e0 = rowptr[node];
    int e1 = rowptr[node + 1];

    half8 sv = *(const half8*)(hb + (size_t)(unsigned)node * 128 + t * 8);
    const float4* b4 = (const float4*)bias;
    float4 blo = b4[t * 2 + 0];
    float4 bhi = b4[t * 2 + 1];

    float2 acc[4];
    #pragma unroll
    for (int i = 0; i < 4; ++i) acc[i] = make_float2(0.f, 0.f);

    const unsigned nclamp = (unsigned)n - 1u;
    for (int ce = e0; ce < e1; ce += 64) {
        int cnt = e1 - ce;
        cnt = (cnt < 64) ? cnt : 64;
        int colv = 0, wval = 0;
        if (lane < cnt) {
            unsigned c = (unsigned)srcS[ce + lane];
            c = (c < nclamp) ? c : nclamp;   // defensive clamp (R15)
            colv = (int)c;
            wval = __float_as_int(di * dinv[c]);
        }
        #pragma unroll 2
        for (int d = 0; d < cnt; d += 4) {
            int idx = (d + g) << 2;
            int c   = __builtin_amdgcn_ds_bpermute(idx, colv);
            float w = __int_as_float(__builtin_amdgcn_ds_bpermute(idx, wval));
            const unsigned* hp = (const unsigned*)(hb + (size_t)(unsigned)c * 128 + t * 8);
            uint4 hv = *(const uint4*)hp;
            float2 u0 = h2f2u(hv.x);
            float2 u1 = h2f2u(hv.y);
            float2 u2 = h2f2u(hv.z);
            float2 u3 = h2f2u(hv.w);
            acc[0].x += u0.x * w; acc[0].y += u0.y * w;
            acc[1].x += u1.x * w; acc[1].y += u1.y * w;
            acc[2].x += u2.x * w; acc[2].y += u2.y * w;
            acc[3].x += u3.x * w; acc[3].y += u3.y * w;
        }
    }

    #pragma unroll
    for (int i = 0; i < 4; ++i) {
        acc[i].x += __shfl_xor(acc[i].x, 16);
        acc[i].y += __shfl_xor(acc[i].y, 16);
        acc[i].x += __shfl_xor(acc[i].x, 32);
        acc[i].y += __shfl_xor(acc[i].y, 32);
    }

    float s = di * di;
    float bb[8] = {blo.x, blo.y, blo.z, blo.w, bhi.x, bhi.y, bhi.z, bhi.w};
    half8 o;
    #pragma unroll
    for (int i = 0; i < 8; ++i) {
        float v = ((i & 1) ? acc[i >> 1].y : acc[i >> 1].x) + (float)sv[i] * s + bb[i];
        if (do_relu) v = fmaxf(v, 0.f);
        o[i] = (_Float16)v;
    }
    if (g == 0)
        *(half8*)((_Float16*)out + (size_t)(unsigned)node * 128 + t * 8) = o;
}

// ------------------------------- launch ------------------------------------

extern "C" void kernel_launch(void* const* d_in, const int* in_sizes, int n_in,
                              void* d_out, int out_size, void* d_ws, size_t ws_size,
                              hipStream_t stream) {
    const float* x  = (const float*)d_in[0];
    const int* eidx = (const int*)d_in[1];
    const float* W1 = (const float*)d_in[2];
    const float* b1 = (const float*)d_in[3];
    const float* W2 = (const float*)d_in[4];
    const float* b2 = (const float*)d_in[5];
    const float* Wc = (const float*)d_in[6];
    const float* bc = (const float*)d_in[7];
    float* out = (float*)d_out;

    const int NF = 256, NH = 128, NC = 40;
    const int n = in_sizes[0] / NF;    // 100000
    const int E = in_sizes[1] / 2;     // 1600000
    const int* src = eidx;
    const int* dst = eidx + E;

    const int nblk = (E + EPB - 1) / EPB;          // 196
    const int hm   = NBKT * nblk;                  // 200704
    const int nbA  = (hm + 4095) / 4096;           // 49

    char* wsb = (char*)d_ws;
    size_t off = 0;
    auto alloc = [&](size_t bytes) {
        char* p = wsb + off;
        off = (off + bytes + 511) & ~(size_t)511;
        return p;
    };
    _Float16* hbuf = (_Float16*)alloc((size_t)n * NH * 2);  // 25.6 MB
    _Float16* abuf = (_Float16*)alloc((size_t)n * NH * 2);  // 25.6 MB
    _Float16* W1t  = (_Float16*)alloc((size_t)128 * 256 * 2);
    _Float16* W2t  = (_Float16*)alloc((size_t)128 * 128 * 2);
    _Float16* Wct  = (_Float16*)alloc((size_t)48 * 128 * 2);
    unsigned long long* eB = (unsigned long long*)alloc((size_t)E * 8);  // 12.8 MB
    int* srcS      = (int*)alloc((size_t)E * 4);            // 6.4 MB
    int* histM     = (int*)alloc((size_t)hm * 4);
    int* histS     = (int*)alloc((size_t)hm * 4);
    int* rowptr    = (int*)alloc((size_t)(n + 1) * 4);
    float* dinv    = (float*)alloc((size_t)n * 4);
    int* bsumA     = (int*)alloc(1024);

    // ---- CSR build: 2-level bucket sort, no global atomics ----
    k_histA<<<nblk, 256, 0, stream>>>(dst, histM, E, nblk);
    k_scan1<16><<<nbA, 256, 0, stream>>>(histM, bsumA, hm);
    k_scan3f<16><<<nbA, 256, 0, stream>>>(histM, bsumA, histS, hm, nbA);
    k_scatterA<<<nblk, 256, 0, stream>>>(src, dst, histS, eB, E, nblk);
    k_sortB<<<NBKT, 256, 0, stream>>>(eB, histS, srcS, rowptr, dinv, n, E, nblk);

    // ---- weights (fused) ----
    k_wcast_all<<<(32768 + 16384 + 6144 + 255) / 256, 256, 0, stream>>>(
        W1, W1t, W2, W2t, Wc, Wct);

    // ---- layers ----
    const int gB = (n + 63) / 64;   // 1563 blocks, 64 rows each
    gemm_pf<256, 128, float, _Float16><<<gB, 256, 0, stream>>>(x, W1t, nullptr, hbuf, n, NH);
    gcn_agg<<<(n + 3) / 4, 256, 0, stream>>>((const unsigned int*)hbuf, rowptr, srcS, dinv, b1,
                                             (unsigned int*)abuf, n, 1);
    gemm_pf<128, 128, _Float16, _Float16><<<gB, 256, 0, stream>>>(abuf, W2t, nullptr, hbuf, n, NH);
    gcn_agg<<<(n + 3) / 4, 256, 0, stream>>>((const unsigned int*)hbuf, rowptr, srcS, dinv, b2,
                                             (unsigned int*)abuf, n, 1);
    gemm_pf<128, 48, _Float16, float><<<gB, 256, 0, stream>>>(abuf, Wct, bc, out, n, NC);
}